// Round 20
// baseline (132.740 us; speedup 1.0000x reference)
//
#include <hip/hip_runtime.h>
#include <hip/hip_bf16.h>

typedef __attribute__((ext_vector_type(8))) short short8;
typedef __attribute__((ext_vector_type(4))) float f32x4;
typedef __attribute__((ext_vector_type(16))) float f32x16;

#define KFC   131072   // 128*32*32
#define NCLS  1000

__device__ __forceinline__ unsigned short f2bf(float f) {
  union { float f; unsigned u; } v; v.f = f;
  unsigned r = v.u + 0x7FFFu + ((v.u >> 16) & 1u);   // RNE
  return (unsigned short)(r >> 16);
}

__device__ __forceinline__ unsigned pk2bf(float a, float b) {
  __hip_bfloat162 h = __float22bfloat162_rn(float2{a, b});
  union { __hip_bfloat162 h; unsigned u; } c; c.h = h;
  return c.u;
}

// ---------------------------------------------------------------------------
// merged weight prep: w2 -> Bp (32x32x16 layout) and w1 -> Bp1.
// Bp[((pos*4+c4)*128 + o)*16 + c] = bf16(w2[o][(c4*16+c)*9 + pos])
// Bp1[o*32 + k] = bf16(w1[o][k]) (k<27), else 0
// ---------------------------------------------------------------------------
__global__ __launch_bounds__(256) void prep_w(
    const float* __restrict__ w2, const float* __restrict__ w1,
    short* __restrict__ Bp, short* __restrict__ Bp1) {
  int i = blockIdx.x * 256 + threadIdx.x;   // 75776 total
  if (i < 73728) {
    int c = i & 15, o = (i >> 4) & 127, q = i >> 11;   // q 0..35
    int pos = q >> 2, c4 = q & 3;
    Bp[i] = (short)f2bf(w2[o * 576 + (c4 * 16 + c) * 9 + pos]);
  } else if (i < 75776) {
    int j = i - 73728;
    int o = j >> 5, k = j & 31;
    Bp1[j] = (k < 27) ? (short)f2bf(w1[o * 27 + k]) : (short)0;
  }
}

// ---------------------------------------------------------------------------
// conv1 via MFMA: x[64,3,128,128] fp32 -> y[64,64,64,64] bf16 NHWC.
// ---------------------------------------------------------------------------
__global__ __launch_bounds__(256) void conv1_mfma(
    const float* __restrict__ x, const short* __restrict__ Bp1,
    const float* __restrict__ b1, unsigned short* __restrict__ y) {
  __shared__ unsigned short tile[1152];     // [3][18][20] = 1080, rest zeroed
  const int t = threadIdx.x;
  const int blk = blockIdx.x;               // b*64 + ty*8 + tx
  const int tx = blk & 7, ty = (blk >> 3) & 7, b = blk >> 6;
  const int w = t >> 6, lane = t & 63;
  const int l15 = lane & 15, lg = lane >> 4;

  const int ih0 = ty * 16 - 1, iw0 = tx * 16 - 1;
  for (int i = t; i < 1152; i += 256) {
    unsigned short v = 0;
    if (i < 1080) {
      int ci = i / 360, rem = i - ci * 360;
      int tr = rem / 20, tc = rem - tr * 20;
      int ih = ih0 + tr, iw = iw0 + tc;
      if (tc < 18 && (unsigned)ih < 128u && (unsigned)iw < 128u)
        v = f2bf(x[(b * 3 + ci) * 16384 + (ih << 7) + iw]);
    }
    tile[i] = v;
  }

  short8 bf[4];
#pragma unroll
  for (int n = 0; n < 4; ++n)
    bf[n] = *(const short8*)(Bp1 + ((n * 16 + l15) << 5) + (lg << 3));

  int soff[8];
#pragma unroll
  for (int j = 0; j < 8; ++j) {
    int k = lg * 8 + j;
    if (k < 27) {
      int ci = k / 9, rem = k - ci * 9;
      int r = rem / 3, s = rem - r * 3;
      soff[j] = ci * 360 + r * 20 + s + l15 + w * 80;
    } else {
      soff[j] = 1080;
    }
  }
  __syncthreads();

  f32x4 acc[4][4];
#pragma unroll
  for (int m = 0; m < 4; ++m)
#pragma unroll
    for (int n = 0; n < 4; ++n) acc[m][n] = (f32x4){0.f, 0.f, 0.f, 0.f};

#pragma unroll
  for (int m = 0; m < 4; ++m) {
    union { short8 s; unsigned short u[8]; } af;
#pragma unroll
    for (int j = 0; j < 8; ++j) af.u[j] = tile[soff[j] + m * 20];
#pragma unroll
    for (int n = 0; n < 4; ++n)
      acc[m][n] = __builtin_amdgcn_mfma_f32_16x16x32_bf16(af.s, bf[n], acc[m][n], 0, 0, 0);
  }

#pragma unroll
  for (int n = 0; n < 4; ++n) {
    const int o = n * 16 + l15;
    const float bias = b1[o];
#pragma unroll
    for (int q = 0; q < 2; ++q) {
      const int pr = ty * 8 + w * 2 + q;
      float v0 = fmaxf(fmaxf(acc[2 * q][n][0], acc[2 * q][n][1]),
                       fmaxf(acc[2 * q + 1][n][0], acc[2 * q + 1][n][1]));
      float v1 = fmaxf(fmaxf(acc[2 * q][n][2], acc[2 * q][n][3]),
                       fmaxf(acc[2 * q + 1][n][2], acc[2 * q + 1][n][3]));
      v0 = fmaxf(v0 + bias, 0.f);
      v1 = fmaxf(v1 + bias, 0.f);
      const int pc = tx * 8 + lg * 2;
      unsigned short* dst = y + ((((size_t)b << 6) + pr) << 12) + ((size_t)pc << 6) + o;
      dst[0]  = f2bf(v0);
      dst[64] = f2bf(v1);
    }
  }
}

// ---------------------------------------------------------------------------
// conv2 v10: 32x32x16 MFMA with rc row-caching. Loop order (c4, kw) outer
// [12 iters]: load 9 row-frags once (rows arow+0..8 at col acol+kw), all
// 3 kh x 4 strips consume rc[2s+kh]. af LDS reads 144 -> 108/wave (-25%,
// ~96 B/cyc < 128 peak). Distance-1 double-buffer (rcb/bfb x2, ~185 VGPR,
// 2 waves/SIMD bracket). Same staging/epilogue as v9 (refcheck'd).
// ---------------------------------------------------------------------------
__global__ __launch_bounds__(256) void conv2_mfma(
    const short* __restrict__ yin, const short* __restrict__ Bp,
    const float* __restrict__ b2, unsigned int* __restrict__ A32) {
  __shared__ short tile[180 * 72];
  const int t = threadIdx.x;
  const int blk = blockIdx.x;                 // ((b*8 + ty)*4 + tx)
  const int tx = blk & 3, ty = (blk >> 2) & 7, b = blk >> 5;
  const int w = t >> 6, lane = t & 63;
  const int l31 = lane & 31, h = lane >> 5;

  const int ih0 = ty * 8 - 1, iw0 = tx * 16 - 1;

  // stage 10x18 px x 64 ch once
  for (int i = t; i < 1440; i += 256) {
    int p = i >> 3, q8 = i & 7;
    int sy = p / 18, sx = p - sy * 18;
    int ih = ih0 + sy, iw = iw0 + sx;
    short8 v = (short8){0, 0, 0, 0, 0, 0, 0, 0};
    if (((unsigned)ih < 64u) && ((unsigned)iw < 64u))
      v = *(const short8*)(yin + ((((size_t)b << 6) + ih) << 12) + ((size_t)iw << 6) + q8 * 8);
    *(short8*)&tile[p * 72 + q8 * 8] = v;
  }
  __syncthreads();

  f32x16 acc[4];
#pragma unroll
  for (int s = 0; s < 4; ++s)
#pragma unroll
    for (int j = 0; j < 16; ++j) acc[s][j] = 0.f;

  const int arow = l31 >> 4;        // px row within strip (0/1)
  const int acol = l31 & 15;        // px col
  const int chof = h * 8;
  const int obase = w * 32 + l31;

  short8 rcb[2][9];
  short8 bfb[2][3];

  // prologue: iter 0 = (c4=0, kw=0)
#pragma unroll
  for (int j = 0; j < 9; ++j)
    rcb[0][j] = *(const short8*)&tile[((j + arow) * 18 + acol) * 72 + chof];
#pragma unroll
  for (int kh = 0; kh < 3; ++kh)
    bfb[0][kh] = *(const short8*)(Bp + (size_t)((kh * 3) * 4 * 128 + obase) * 16 + chof);

#pragma unroll
  for (int it = 0; it < 12; ++it) {
    const int c4 = it / 3, kw = it - 3 * c4;
    (void)c4; (void)kw;
    if (it < 11) {
      const int nit = it + 1, nc4 = nit / 3, nkw = nit - 3 * nc4;
#pragma unroll
      for (int j = 0; j < 9; ++j)
        rcb[nit & 1][j] = *(const short8*)&tile[((j + arow) * 18 + acol + nkw) * 72 + nc4 * 16 + chof];
#pragma unroll
      for (int kh = 0; kh < 3; ++kh)
        bfb[nit & 1][kh] = *(const short8*)(Bp + (size_t)((((kh * 3 + nkw) * 4 + nc4) * 128) + obase) * 16 + chof);
    }
#pragma unroll
    for (int kh = 0; kh < 3; ++kh)
#pragma unroll
      for (int s = 0; s < 4; ++s)
        acc[s] = __builtin_amdgcn_mfma_f32_32x32x16_bf16(rcb[it & 1][2 * s + kh], bfb[it & 1][kh], acc[s], 0, 0, 0);
  }

  // epilogue: bias + relu + 2x2 pool (fully in-lane), identical to v9.
  const size_t bbase = ((size_t)b << 16);   // u32 units
  const float bias = b2[obase];
#pragma unroll
  for (int s = 0; s < 4; ++s) {
    const int prow = ty * 4 + s;
    float v0 = fmaxf(fmaxf(acc[s][0], acc[s][1]), fmaxf(acc[s][8],  acc[s][9]));
    float v1 = fmaxf(fmaxf(acc[s][2], acc[s][3]), fmaxf(acc[s][10], acc[s][11]));
    float v2 = fmaxf(fmaxf(acc[s][4], acc[s][5]), fmaxf(acc[s][12], acc[s][13]));
    float v3 = fmaxf(fmaxf(acc[s][6], acc[s][7]), fmaxf(acc[s][14], acc[s][15]));
    v0 = fmaxf(v0 + bias, 0.f);
    v1 = fmaxf(v1 + bias, 0.f);
    v2 = fmaxf(v2 + bias, 0.f);
    v3 = fmaxf(v3 + bias, 0.f);
    unsigned int* dst = A32 + bbase + (size_t)obase * 512 + prow * 16 + tx * 4 + h;
    dst[0] = (unsigned)f2bf(v0) | ((unsigned)f2bf(v1) << 16);
    dst[2] = (unsigned)f2bf(v2) | ((unsigned)f2bf(v3) << 16);
  }
}

// ---------------------------------------------------------------------------
// fc1 v6: K-chunk 512, nt-split 2 (unchanged).
// ---------------------------------------------------------------------------
__global__ __launch_bounds__(256) void fc1_mfma(
    const unsigned short* __restrict__ A, const float* __restrict__ W,
    float* __restrict__ P) {
  __shared__ short Al[64][520];
  const int t = threadIdx.x;
  const int blk = blockIdx.x;                 // kc*2 + nt
  const int kc = blk >> 1, nt = blk & 1;
  const int wn = t >> 6, lane = t & 63;
  const int l15 = lane & 15, lg = lane >> 4;

  {
    const int row = t >> 2, q = t & 3;
    const unsigned short* asrc = A + (size_t)row * KFC + kc * 512 + q * 128;
    short8 ar[16];
#pragma unroll
    for (int i = 0; i < 16; ++i) ar[i] = *(const short8*)(asrc + i * 8);
#pragma unroll
    for (int i = 0; i < 16; ++i) *(short8*)&Al[row][q * 128 + i * 8] = ar[i];
  }
  __syncthreads();

  f32x4 acc[4][2];
#pragma unroll
  for (int m = 0; m < 4; ++m)
#pragma unroll
    for (int n = 0; n < 2; ++n) acc[m][n] = (f32x4){0.f, 0.f, 0.f, 0.f};

  const float* wrow[2];
#pragma unroll
  for (int n = 0; n < 2; ++n)
    wrow[n] = W + (size_t)(nt * 128 + wn * 32 + n * 16 + l15) * KFC + kc * 512 + lg * 8;

#pragma unroll
  for (int ks = 0; ks < 16; ++ks) {
    short8 bf[2];
#pragma unroll
    for (int n = 0; n < 2; ++n) {
      f32x4 u = *(const f32x4*)(wrow[n] + ks * 32);
      f32x4 v = *(const f32x4*)(wrow[n] + ks * 32 + 4);
      union { short8 s; unsigned u32[4]; } pk;
      pk.u32[0] = pk2bf(u[0], u[1]);
      pk.u32[1] = pk2bf(u[2], u[3]);
      pk.u32[2] = pk2bf(v[0], v[1]);
      pk.u32[3] = pk2bf(v[2], v[3]);
      bf[n] = pk.s;
    }
    short8 af[4];
#pragma unroll
    for (int m = 0; m < 4; ++m)
      af[m] = *(const short8*)&Al[m * 16 + l15][ks * 32 + lg * 8];
#pragma unroll
    for (int n = 0; n < 2; ++n)
#pragma unroll
      for (int m = 0; m < 4; ++m)
        acc[m][n] = __builtin_amdgcn_mfma_f32_16x16x32_bf16(af[m], bf[n], acc[m][n], 0, 0, 0);
  }

  float* dst = P + (size_t)kc * 16384;
#pragma unroll
  for (int m = 0; m < 4; ++m)
#pragma unroll
    for (int n = 0; n < 2; ++n)
#pragma unroll
      for (int j = 0; j < 4; ++j) {
        int brow = m * 16 + lg * 4 + j;
        int o = nt * 128 + wn * 32 + n * 16 + l15;
        dst[brow * 256 + o] = acc[m][n][j];
      }
}

// fc1 partial reduce + bias + relu -> Y[64,256]. 256 blocks, coalesced.
__global__ __launch_bounds__(256) void fc1_reduce_kernel(
    const float* __restrict__ P, const float* __restrict__ fb1,
    float* __restrict__ Y) {
  __shared__ float red[4][64];
  const int t = threadIdx.x;
  const int iq = t & 63, pg = t >> 6;
  const int gidx = blockIdx.x * 64 + iq;
  const float* p0 = P + (size_t)(pg * 64) * 16384 + gidx;
  float s0 = 0, s1 = 0, s2 = 0, s3 = 0;
  for (int p = 0; p < 64; p += 4) {
    s0 += p0[(size_t)(p + 0) * 16384];
    s1 += p0[(size_t)(p + 1) * 16384];
    s2 += p0[(size_t)(p + 2) * 16384];
    s3 += p0[(size_t)(p + 3) * 16384];
  }
  red[pg][iq] = (s0 + s1) + (s2 + s3);
  __syncthreads();
  if (pg == 0) {
    float tot = (red[0][iq] + red[1][iq]) + (red[2][iq] + red[3][iq]);
    Y[gidx] = fmaxf(tot + fb1[gidx & 255], 0.f);
  }
}

// fc2: out[64,1000] = Y[64,256] @ W2[1000,256]^T + b2
__global__ __launch_bounds__(256) void fc2_kernel(
    const float* __restrict__ Y, const float* __restrict__ W2,
    const float* __restrict__ b2, float* __restrict__ out) {
  int tid = blockIdx.x * 256 + threadIdx.x;
  if (tid >= 64 * NCLS) return;
  int b = tid / NCLS, n = tid - b * NCLS;
  const float4* yv = (const float4*)(Y + b * 256);
  const float4* wv = (const float4*)(W2 + n * 256);
  float acc = 0.f;
#pragma unroll 8
  for (int f = 0; f < 64; ++f) {
    float4 a = yv[f], w = wv[f];
    acc += a.x * w.x + a.y * w.y + a.z * w.z + a.w * w.w;
  }
  out[tid] = acc + b2[n];
}

// ---------------------------------------------------------------------------
extern "C" void kernel_launch(void* const* d_in, const int* in_sizes, int n_in,
                              void* d_out, int out_size, void* d_ws, size_t ws_size,
                              hipStream_t stream) {
  const float* x   = (const float*)d_in[0];
  const float* w1  = (const float*)d_in[1];
  const float* b1  = (const float*)d_in[2];
  const float* w2  = (const float*)d_in[3];
  const float* b2  = (const float*)d_in[4];
  const float* fw1 = (const float*)d_in[5];
  const float* fb1 = (const float*)d_in[6];
  const float* fw2 = (const float*)d_in[7];
  const float* fb2 = (const float*)d_in[8];
  float* out = (float*)d_out;

  unsigned short* Y1 = (unsigned short*)d_ws;              // conv1 out bf16 NHWC [16777216]
  unsigned short* A16 = Y1 + 16777216;                     // conv2 out bf16 [8388608]
  short* Bp = (short*)(A16 + 8388608);                     // conv2 weights bf16 [73728]
  short* Bp1 = Bp + 73728;                                 // conv1 weights bf16 [2048]
  float* P  = (float*)(Bp1 + 2048);                        // fc1 partials [256*16384]
  float* Yf = P + 4194304;                                 // fc1 out [16384]

  prep_w<<<296, 256, 0, stream>>>(w2, w1, Bp, Bp1);
  conv1_mfma<<<4096, 256, 0, stream>>>(x, Bp1, b1, Y1);
  conv2_mfma<<<2048, 256, 0, stream>>>((const short*)Y1, Bp, b2, (unsigned int*)A16);
  fc1_mfma<<<512, 256, 0, stream>>>(A16, fw1, P);
  fc1_reduce_kernel<<<256, 256, 0, stream>>>(P, fb1, Yf);
  fc2_kernel<<<250, 256, 0, stream>>>(Yf, fw2, fb2, out);
}

// Round 21
// 114.703 us; speedup vs baseline: 1.1572x; 1.1572x over previous
//
#include <hip/hip_runtime.h>
#include <hip/hip_bf16.h>

typedef __attribute__((ext_vector_type(8))) short short8;
typedef __attribute__((ext_vector_type(4))) float f32x4;

#define KFC   131072   // 128*32*32
#define NCLS  1000

__device__ __forceinline__ unsigned short f2bf(float f) {
  union { float f; unsigned u; } v; v.f = f;
  unsigned r = v.u + 0x7FFFu + ((v.u >> 16) & 1u);   // RNE
  return (unsigned short)(r >> 16);
}

__device__ __forceinline__ unsigned pk2bf(float a, float b) {
  __hip_bfloat162 h = __float22bfloat162_rn(float2{a, b});
  union { __hip_bfloat162 h; unsigned u; } c; c.h = h;
  return c.u;
}

// ---------------------------------------------------------------------------
// merged weight prep (v8 layouts):
// Bp[((cg*9+pos)*128 + o)*32 + c] = bf16(w2[o][(cg*32+c)*9 + pos])
// Bp1[o*32 + k] = bf16(w1[o][k]) (k<27), else 0
// ---------------------------------------------------------------------------
__global__ __launch_bounds__(256) void prep_w(
    const float* __restrict__ w2, const float* __restrict__ w1,
    short* __restrict__ Bp, short* __restrict__ Bp1) {
  int i = blockIdx.x * 256 + threadIdx.x;   // 75776 total
  if (i < 73728) {
    int c = i & 31, o = (i >> 5) & 127, pp = i >> 12;
    int cg = pp / 9, pos = pp - cg * 9;
    Bp[i] = (short)f2bf(w2[o * 576 + (cg * 32 + c) * 9 + pos]);
  } else if (i < 75776) {
    int j = i - 73728;
    int o = j >> 5, k = j & 31;
    Bp1[j] = (k < 27) ? (short)f2bf(w1[o * 27 + k]) : (short)0;
  }
}

// ---------------------------------------------------------------------------
// conv1 via MFMA: x[64,3,128,128] fp32 -> y[64,64,64,64] bf16 NHWC.
// ---------------------------------------------------------------------------
__global__ __launch_bounds__(256) void conv1_mfma(
    const float* __restrict__ x, const short* __restrict__ Bp1,
    const float* __restrict__ b1, unsigned short* __restrict__ y) {
  __shared__ unsigned short tile[1152];     // [3][18][20] = 1080, rest zeroed
  const int t = threadIdx.x;
  const int blk = blockIdx.x;               // b*64 + ty*8 + tx
  const int tx = blk & 7, ty = (blk >> 3) & 7, b = blk >> 6;
  const int w = t >> 6, lane = t & 63;
  const int l15 = lane & 15, lg = lane >> 4;

  const int ih0 = ty * 16 - 1, iw0 = tx * 16 - 1;
  for (int i = t; i < 1152; i += 256) {
    unsigned short v = 0;
    if (i < 1080) {
      int ci = i / 360, rem = i - ci * 360;
      int tr = rem / 20, tc = rem - tr * 20;
      int ih = ih0 + tr, iw = iw0 + tc;
      if (tc < 18 && (unsigned)ih < 128u && (unsigned)iw < 128u)
        v = f2bf(x[(b * 3 + ci) * 16384 + (ih << 7) + iw]);
    }
    tile[i] = v;
  }

  short8 bf[4];
#pragma unroll
  for (int n = 0; n < 4; ++n)
    bf[n] = *(const short8*)(Bp1 + ((n * 16 + l15) << 5) + (lg << 3));

  int soff[8];
#pragma unroll
  for (int j = 0; j < 8; ++j) {
    int k = lg * 8 + j;
    if (k < 27) {
      int ci = k / 9, rem = k - ci * 9;
      int r = rem / 3, s = rem - r * 3;
      soff[j] = ci * 360 + r * 20 + s + l15 + w * 80;
    } else {
      soff[j] = 1080;
    }
  }
  __syncthreads();

  f32x4 acc[4][4];
#pragma unroll
  for (int m = 0; m < 4; ++m)
#pragma unroll
    for (int n = 0; n < 4; ++n) acc[m][n] = (f32x4){0.f, 0.f, 0.f, 0.f};

#pragma unroll
  for (int m = 0; m < 4; ++m) {
    union { short8 s; unsigned short u[8]; } af;
#pragma unroll
    for (int j = 0; j < 8; ++j) af.u[j] = tile[soff[j] + m * 20];
#pragma unroll
    for (int n = 0; n < 4; ++n)
      acc[m][n] = __builtin_amdgcn_mfma_f32_16x16x32_bf16(af.s, bf[n], acc[m][n], 0, 0, 0);
  }

#pragma unroll
  for (int n = 0; n < 4; ++n) {
    const int o = n * 16 + l15;
    const float bias = b1[o];
#pragma unroll
    for (int q = 0; q < 2; ++q) {
      const int pr = ty * 8 + w * 2 + q;
      float v0 = fmaxf(fmaxf(acc[2 * q][n][0], acc[2 * q][n][1]),
                       fmaxf(acc[2 * q + 1][n][0], acc[2 * q + 1][n][1]));
      float v1 = fmaxf(fmaxf(acc[2 * q][n][2], acc[2 * q][n][3]),
                       fmaxf(acc[2 * q + 1][n][2], acc[2 * q + 1][n][3]));
      v0 = fmaxf(v0 + bias, 0.f);
      v1 = fmaxf(v1 + bias, 0.f);
      const int pc = tx * 8 + lg * 2;
      unsigned short* dst = y + ((((size_t)b << 6) + pr) << 12) + ((size_t)pc << 6) + o;
      dst[0]  = f2bf(v0);
      dst[64] = f2bf(v1);
    }
  }
}

// ---------------------------------------------------------------------------
// conv2 v8 (best measured, R18): 16x16x32, LDS stride 36, distance-2 af /
// distance-4 bf prefetch. block = 256 thr = 4 waves; wave = 8 conv rows x
// 32 o; grid 2048.
// ---------------------------------------------------------------------------
__global__ __launch_bounds__(256) void conv2_mfma(
    const short* __restrict__ yin, const short* __restrict__ Bp,
    const float* __restrict__ b2, unsigned int* __restrict__ A32) {
  __shared__ short tile[180 * 36];
  const int t = threadIdx.x;
  const int blk = blockIdx.x;
  const int tx = blk & 3, ty = (blk >> 2) & 7, b = blk >> 5;
  const int w = t >> 6, lane = t & 63;
  const int l15 = lane & 15, lg = lane >> 4;

  f32x4 acc[8][2];
#pragma unroll
  for (int m = 0; m < 8; ++m)
#pragma unroll
    for (int n = 0; n < 2; ++n) acc[m][n] = (f32x4){0.f, 0.f, 0.f, 0.f};

  const int ih0 = ty * 8 - 1, iw0 = tx * 16 - 1;
  const int abase = l15 * 36 + lg * 8;

#pragma unroll
  for (int cg = 0; cg < 2; ++cg) {
    __syncthreads();
    for (int i = t; i < 180 * 4; i += 256) {
      int p = i >> 2, q = i & 3;
      int sy = p / 18, sx = p - sy * 18;
      int ih = ih0 + sy, iw = iw0 + sx;
      short8 v = (short8){0, 0, 0, 0, 0, 0, 0, 0};
      if (((unsigned)ih < 64u) && ((unsigned)iw < 64u))
        v = *(const short8*)(yin + ((((size_t)b << 6) + ih) << 12) + ((size_t)iw << 6) + cg * 32 + q * 8);
      *(short8*)&tile[p * 36 + q * 8] = v;
    }
    __syncthreads();

    short8 afb[3][4];
    short8 bfb[3][2];

#pragma unroll
    for (int p = 0; p < 2; ++p)
#pragma unroll
      for (int n = 0; n < 2; ++n)
        bfb[p][n] = *(const short8*)(Bp + ((((cg * 9 + p) << 7) + (w * 2 + n) * 16 + l15) << 5) + (lg << 3));
#pragma unroll
    for (int ss = 0; ss < 2; ++ss) {
      const int ph = ss & 1;
#pragma unroll
      for (int m = 0; m < 4; ++m)
        afb[ss][m] = *(const short8*)&tile[(ph * 4 + m) * 648 + abase];
    }

#pragma unroll
    for (int s = 0; s < 18; ++s) {
      const int pos = s >> 1, half = s & 1;
      if (half == 0 && pos + 2 <= 8) {
        const int np = pos + 2;
#pragma unroll
        for (int n = 0; n < 2; ++n)
          bfb[np % 3][n] = *(const short8*)(Bp + ((((cg * 9 + np) << 7) + (w * 2 + n) * 16 + l15) << 5) + (lg << 3));
      }
      if (s < 16) {
        const int ns = s + 2, npos = ns >> 1, nhalf = ns & 1;
        const int nkh = npos / 3, nkw = npos - nkh * 3;
#pragma unroll
        for (int m = 0; m < 4; ++m)
          afb[ns % 3][m] = *(const short8*)&tile[(nhalf * 4 + m + nkh) * 648 + nkw * 36 + abase];
      }
#pragma unroll
      for (int n = 0; n < 2; ++n)
#pragma unroll
        for (int m = 0; m < 4; ++m)
          acc[half * 4 + m][n] = __builtin_amdgcn_mfma_f32_16x16x32_bf16(
              afb[s % 3][m], bfb[pos % 3][n], acc[half * 4 + m][n], 0, 0, 0);
    }
  }

  const size_t bbase = ((size_t)b << 16);   // u32 units
#pragma unroll
  for (int n = 0; n < 2; ++n) {
    const int o = (w * 2 + n) * 16 + l15;
    const float bias = b2[o];
#pragma unroll
    for (int mp = 0; mp < 4; ++mp) {
      const int prow = ty * 4 + mp;
      float v0 = fmaxf(fmaxf(acc[2 * mp][n][0], acc[2 * mp][n][1]),
                       fmaxf(acc[2 * mp + 1][n][0], acc[2 * mp + 1][n][1]));
      float v1 = fmaxf(fmaxf(acc[2 * mp][n][2], acc[2 * mp][n][3]),
                       fmaxf(acc[2 * mp + 1][n][2], acc[2 * mp + 1][n][3]));
      v0 = fmaxf(v0 + bias, 0.f);
      v1 = fmaxf(v1 + bias, 0.f);
      unsigned pk = (unsigned)f2bf(v0) | ((unsigned)f2bf(v1) << 16);
      A32[bbase + (size_t)o * 512 + prow * 16 + tx * 4 + lg] = pk;
    }
  }
}

// ---------------------------------------------------------------------------
// fc1 v6: K-chunk 512, nt-split 2 (unchanged).
// ---------------------------------------------------------------------------
__global__ __launch_bounds__(256) void fc1_mfma(
    const unsigned short* __restrict__ A, const float* __restrict__ W,
    float* __restrict__ P) {
  __shared__ short Al[64][520];
  const int t = threadIdx.x;
  const int blk = blockIdx.x;                 // kc*2 + nt
  const int kc = blk >> 1, nt = blk & 1;
  const int wn = t >> 6, lane = t & 63;
  const int l15 = lane & 15, lg = lane >> 4;

  {
    const int row = t >> 2, q = t & 3;
    const unsigned short* asrc = A + (size_t)row * KFC + kc * 512 + q * 128;
    short8 ar[16];
#pragma unroll
    for (int i = 0; i < 16; ++i) ar[i] = *(const short8*)(asrc + i * 8);
#pragma unroll
    for (int i = 0; i < 16; ++i) *(short8*)&Al[row][q * 128 + i * 8] = ar[i];
  }
  __syncthreads();

  f32x4 acc[4][2];
#pragma unroll
  for (int m = 0; m < 4; ++m)
#pragma unroll
    for (int n = 0; n < 2; ++n) acc[m][n] = (f32x4){0.f, 0.f, 0.f, 0.f};

  const float* wrow[2];
#pragma unroll
  for (int n = 0; n < 2; ++n)
    wrow[n] = W + (size_t)(nt * 128 + wn * 32 + n * 16 + l15) * KFC + kc * 512 + lg * 8;

#pragma unroll
  for (int ks = 0; ks < 16; ++ks) {
    short8 bf[2];
#pragma unroll
    for (int n = 0; n < 2; ++n) {
      f32x4 u = *(const f32x4*)(wrow[n] + ks * 32);
      f32x4 v = *(const f32x4*)(wrow[n] + ks * 32 + 4);
      union { short8 s; unsigned u32[4]; } pk;
      pk.u32[0] = pk2bf(u[0], u[1]);
      pk.u32[1] = pk2bf(u[2], u[3]);
      pk.u32[2] = pk2bf(v[0], v[1]);
      pk.u32[3] = pk2bf(v[2], v[3]);
      bf[n] = pk.s;
    }
    short8 af[4];
#pragma unroll
    for (int m = 0; m < 4; ++m)
      af[m] = *(const short8*)&Al[m * 16 + l15][ks * 32 + lg * 8];
#pragma unroll
    for (int n = 0; n < 2; ++n)
#pragma unroll
      for (int m = 0; m < 4; ++m)
        acc[m][n] = __builtin_amdgcn_mfma_f32_16x16x32_bf16(af[m], bf[n], acc[m][n], 0, 0, 0);
  }

  float* dst = P + (size_t)kc * 16384;
#pragma unroll
  for (int m = 0; m < 4; ++m)
#pragma unroll
    for (int n = 0; n < 2; ++n)
#pragma unroll
      for (int j = 0; j < 4; ++j) {
        int brow = m * 16 + lg * 4 + j;
        int o = nt * 128 + wn * 32 + n * 16 + l15;
        dst[brow * 256 + o] = acc[m][n][j];
      }
}

// fc1 partial reduce + bias + relu -> Y[64,256]. 256 blocks, coalesced.
__global__ __launch_bounds__(256) void fc1_reduce_kernel(
    const float* __restrict__ P, const float* __restrict__ fb1,
    float* __restrict__ Y) {
  __shared__ float red[4][64];
  const int t = threadIdx.x;
  const int iq = t & 63, pg = t >> 6;
  const int gidx = blockIdx.x * 64 + iq;
  const float* p0 = P + (size_t)(pg * 64) * 16384 + gidx;
  float s0 = 0, s1 = 0, s2 = 0, s3 = 0;
  for (int p = 0; p < 64; p += 4) {
    s0 += p0[(size_t)(p + 0) * 16384];
    s1 += p0[(size_t)(p + 1) * 16384];
    s2 += p0[(size_t)(p + 2) * 16384];
    s3 += p0[(size_t)(p + 3) * 16384];
  }
  red[pg][iq] = (s0 + s1) + (s2 + s3);
  __syncthreads();
  if (pg == 0) {
    float tot = (red[0][iq] + red[1][iq]) + (red[2][iq] + red[3][iq]);
    Y[gidx] = fmaxf(tot + fb1[gidx & 255], 0.f);
  }
}

// fc2: out[64,1000] = Y[64,256] @ W2[1000,256]^T + b2
__global__ __launch_bounds__(256) void fc2_kernel(
    const float* __restrict__ Y, const float* __restrict__ W2,
    const float* __restrict__ b2, float* __restrict__ out) {
  int tid = blockIdx.x * 256 + threadIdx.x;
  if (tid >= 64 * NCLS) return;
  int b = tid / NCLS, n = tid - b * NCLS;
  const float4* yv = (const float4*)(Y + b * 256);
  const float4* wv = (const float4*)(W2 + n * 256);
  float acc = 0.f;
#pragma unroll 8
  for (int f = 0; f < 64; ++f) {
    float4 a = yv[f], w = wv[f];
    acc += a.x * w.x + a.y * w.y + a.z * w.z + a.w * w.w;
  }
  out[tid] = acc + b2[n];
}

// ---------------------------------------------------------------------------
extern "C" void kernel_launch(void* const* d_in, const int* in_sizes, int n_in,
                              void* d_out, int out_size, void* d_ws, size_t ws_size,
                              hipStream_t stream) {
  const float* x   = (const float*)d_in[0];
  const float* w1  = (const float*)d_in[1];
  const float* b1  = (const float*)d_in[2];
  const float* w2  = (const float*)d_in[3];
  const float* b2  = (const float*)d_in[4];
  const float* fw1 = (const float*)d_in[5];
  const float* fb1 = (const float*)d_in[6];
  const float* fw2 = (const float*)d_in[7];
  const float* fb2 = (const float*)d_in[8];
  float* out = (float*)d_out;

  unsigned short* Y1 = (unsigned short*)d_ws;              // conv1 out bf16 NHWC [16777216]
  unsigned short* A16 = Y1 + 16777216;                     // conv2 out bf16 [8388608]
  short* Bp = (short*)(A16 + 8388608);                     // conv2 weights bf16 [73728]
  short* Bp1 = Bp + 73728;                                 // conv1 weights bf16 [2048]
  float* P  = (float*)(Bp1 + 2048);                        // fc1 partials [256*16384]
  float* Yf = P + 4194304;                                 // fc1 out [16384]

  prep_w<<<296, 256, 0, stream>>>(w2, w1, Bp, Bp1);
  conv1_mfma<<<4096, 256, 0, stream>>>(x, Bp1, b1, Y1);
  conv2_mfma<<<2048, 256, 0, stream>>>((const short*)Y1, Bp, b2, (unsigned int*)A16);
  fc1_mfma<<<512, 256, 0, stream>>>(A16, fw1, P);
  fc1_reduce_kernel<<<256, 256, 0, stream>>>(P, fb1, Yf);
  fc2_kernel<<<250, 256, 0, stream>>>(Yf, fw2, fb2, out);
}